// Round 1
// baseline (372.426 us; speedup 1.0000x reference)
//
#include <hip/hip_runtime.h>
#include <cstdint>
#include <cstddef>

// Problem constants: B=4, S=2048, D=1024
#define BB 4
#define SS 2048
#define DD 1024

typedef _Float16 f16;
typedef _Float16 f16x8 __attribute__((ext_vector_type(8)));
typedef _Float16 f16x4 __attribute__((ext_vector_type(4)));
typedef float fx4 __attribute__((ext_vector_type(4)));

// ---------------------------------------------------------------------------
// async global->LDS, 16B per lane. LDS dest must be wave-uniform base + lane*16.
// ---------------------------------------------------------------------------
__device__ __forceinline__ void async_copy16(void* lds, const void* g) {
  __builtin_amdgcn_global_load_lds(
      (__attribute__((address_space(1))) void*)const_cast<void*>(g),
      (__attribute__((address_space(3))) void*)lds,
      16, 0, 0);
}

enum { EPI_BIAS = 0, EPI_MASKEXP = 1, EPI_ROWSCALE = 2, EPI_QKV = 3 };

// ---------------------------------------------------------------------------
// R8: 256x256 tile, BK=64, 512 threads (8 waves 2Mx4N), 8-phase schedule with
// counted vmcnt (T3+T4) + setprio (T5). Replaces the 128^2 2-barrier structure
// (446-668 TF) with the 1563-1728 TF structure from the ladder.
//
// LDS (128KB): 2 parity buffers x { A_k0 16K | A_k1 16K | B_k0 16K | B_k1 16K }
// Each slot is [256 rows][32 f16] (64B rows). Chunk XOR swizzle carried over
// verbatim from R2 (proved SQ_LDS_BANK_CONFLICT=0): staging thread t fetches
// global 16B chunk (t&3)^((t>>3)&3) of its row; reads use chunk quad^((r16>>1)&3).
// DMA dest is linear (d + t*16) as required by global_load_lds.
//
// Pipeline (per-wave vmcnt units; 1 STG_* = 2 insts):
//   prologue: stage tile0 (A_k0,B_k0,A_k1,B_k1 = 8 insts); vmcnt(4) -> k0
//   retired; barrier.
//   tile T (parity T&1), staging targets parity^1 (never the buffer being
//   read -> no overwrite race):
//     ph0: read bf(k0)+af(m0-3,k0); stage A_k0(T+1); bar; 16 MFMA; bar
//     ph1: read af(m4-7,k0);        stage B_k0(T+1); bar; 16 MFMA;
//          vmcnt(4)  [issued=8T+12, retires through B_k1(T) -> ph2/3 safe]; bar
//     ph2: read bf(k1)+af(m0-3,k1); stage A_k1(T+1); bar; 16 MFMA; bar
//     ph3: read af(m4-7,k1);        stage B_k1(T+1); bar; 16 MFMA;
//          vmcnt(4)  [retires through B_k0(T+1) -> next tile ph0/1 safe]; bar
//   Last tile: no staging; ph1 tail uses vmcnt(0) -> fully drained before the
//   epilogue, so epilogue VGPR global loads never coexist with LDS-DMA
//   (R7 hazard rule satisfied structurally).
// Each wave's own vmcnt covers its own DMA slice; the trailing barrier (plus
// sched_barrier(0) to pin compiler ordering) publishes all waves' slices.
//
// EPI_MASKEXP now reads a PRE-PACKED global bitmask (built in k_prep) instead
// of packing in-kernel: removes the 64MB int32 in-dispatch mask read and the
// serial pre-loop pack. 2 broadcast dword loads per (m,r).
// ---------------------------------------------------------------------------
template <typename OutT, int MODE>
__global__ __launch_bounds__(512, 2) void gemm_nt8(
    const f16* __restrict__ A, long long strideA, int lda,
    const f16* __restrict__ Bt, long long strideB, int ldb,
    OutT* __restrict__ C, long long strideC, int ldc,
    const float* __restrict__ bias, const uint32_t* __restrict__ gmask,
    float* __restrict__ rowSum, f16* __restrict__ vt, float scale, int K) {
  __shared__ __align__(16) char smem[131072];

  const int t = threadIdx.x;
  const int lane = t & 63;
  const int wid = t >> 6;
  const long long bz = blockIdx.z;
  const int tileM = blockIdx.y * 256;
  const int tileN = blockIdx.x * 256;

  const f16* Ab = A + bz * strideA;
  const f16* Bb = Bt + bz * strideB;
  OutT* Cb = C + bz * strideC;

  // staging map: thread t covers row t>>2 (inst spans 128 rows), swizzled chunk
  const int gch = ((t & 3) ^ ((t >> 3) & 3)) * 8;
  const f16* pA = Ab + (size_t)(tileM + (t >> 2)) * lda + gch;
  const f16* pB = Bb + (size_t)(tileN + (t >> 2)) * ldb + gch;
  const size_t rA = (size_t)128 * lda;  // +128 rows (second inst of a slot)
  const size_t rB = (size_t)128 * ldb;
  const int tb = t * 16;

  const int waveM = (wid >> 2) * 128;
  const int waveN = (wid & 3) * 64;
  const int r16 = lane & 15;
  const int quad = lane >> 4;
  const int sw = (r16 >> 1) & 3;

  const int nT = K >> 6;

#define STG_A(par, ks, Tn)                                      \
  {                                                             \
    char* d_ = smem + (par) * 65536 + (ks) * 16384;             \
    const f16* s_ = pA + (size_t)(Tn) * 64 + (ks) * 32;         \
    async_copy16(d_ + tb, s_);                                  \
    async_copy16(d_ + 8192 + tb, s_ + rA);                      \
  }
#define STG_B(par, ks, Tn)                                      \
  {                                                             \
    char* d_ = smem + (par) * 65536 + 32768 + (ks) * 16384;     \
    const f16* s_ = pB + (size_t)(Tn) * 64 + (ks) * 32;         \
    async_copy16(d_ + tb, s_);                                  \
    async_copy16(d_ + 8192 + tb, s_ + rB);                      \
  }

  // prologue: tile 0 -> parity 0. Issue order matters: k0 parts first.
  STG_A(0, 0, 0);
  STG_B(0, 0, 0);
  STG_A(0, 1, 0);
  STG_B(0, 1, 0);
  asm volatile("s_waitcnt vmcnt(4)" ::: "memory");
  __builtin_amdgcn_s_barrier();
  __builtin_amdgcn_sched_barrier(0);

  fx4 acc[8][4] = {};
  f16x8 af[4], bf[4];

#define LOADB(Bs)                                                              \
  _Pragma("unroll") for (int j = 0; j < 4; ++j) bf[j] =                        \
      *(const f16x8*)&(Bs)[(waveN + j * 16 + r16) * 32 + (quad ^ sw) * 8];
#define LOADA(As, mo)                                                          \
  _Pragma("unroll") for (int m = 0; m < 4; ++m) af[m] =                        \
      *(const f16x8*)&(As)[(waveM + (mo) + m * 16 + r16) * 32 + (quad ^ sw) * 8];
#define MFMA16(mo)                                                             \
  __builtin_amdgcn_s_setprio(1);                                               \
  _Pragma("unroll") for (int m = 0; m < 4; ++m)                                \
  _Pragma("unroll") for (int j = 0; j < 4; ++j)                                \
      acc[(mo) + m][j] = __builtin_amdgcn_mfma_f32_16x16x32_f16(               \
          af[m], bf[j], acc[(mo) + m][j], 0, 0, 0);                            \
  __builtin_amdgcn_s_setprio(0);

  for (int T = 0; T < nT; ++T) {
    const int par = T & 1;
    const int np = par ^ 1;
    const bool st = (T + 1) < nT;
    const f16* As0 = (const f16*)(smem + par * 65536);
    const f16* As1 = As0 + 8192;
    const f16* Bs0 = As0 + 16384;
    const f16* Bs1 = As0 + 24576;

    // ---- phase 0: k0, m0-3 ----
    LOADB(Bs0);
    LOADA(As0, 0);
    if (st) STG_A(np, 0, T + 1);
    __builtin_amdgcn_s_barrier();
    MFMA16(0);
    __builtin_amdgcn_s_barrier();

    // ---- phase 1: k0, m4-7 ----
    LOADA(As0, 64);
    if (st) STG_B(np, 0, T + 1);
    __builtin_amdgcn_s_barrier();
    MFMA16(4);
    if (st) {
      asm volatile("s_waitcnt vmcnt(4)" ::: "memory");
    } else {
      asm volatile("s_waitcnt vmcnt(0)" ::: "memory");  // last tile: full drain
    }
    __builtin_amdgcn_s_barrier();
    __builtin_amdgcn_sched_barrier(0);

    // ---- phase 2: k1, m0-3 ----
    LOADB(Bs1);
    LOADA(As1, 0);
    if (st) STG_A(np, 1, T + 1);
    __builtin_amdgcn_s_barrier();
    MFMA16(0);
    __builtin_amdgcn_s_barrier();

    // ---- phase 3: k1, m4-7 ----
    LOADA(As1, 64);
    if (st) STG_B(np, 1, T + 1);
    __builtin_amdgcn_s_barrier();
    MFMA16(4);
    if (st) {
      asm volatile("s_waitcnt vmcnt(4)" ::: "memory");
    }
    __builtin_amdgcn_s_barrier();
    __builtin_amdgcn_sched_barrier(0);
  }

  // C/D layout (verified, dtype-independent): col = lane&15, row = quad*4+reg.
  if constexpr (MODE == EPI_BIAS) {
#pragma unroll
    for (int j = 0; j < 4; ++j) {
      const int col = tileN + waveN + j * 16 + r16;
      const float bv = bias[col];
#pragma unroll
      for (int m = 0; m < 8; ++m) {
#pragma unroll
        for (int r = 0; r < 4; ++r) {
          const int row = tileM + waveM + m * 16 + quad * 4 + r;
          Cb[(size_t)row * ldc + col] = (OutT)(acc[m][j][r] * scale + bv);
        }
      }
    }
  } else if constexpr (MODE == EPI_QKV) {
    if (tileN < 2 * DD) {
      // packed QK output [8192 x 2048]
#pragma unroll
      for (int j = 0; j < 4; ++j) {
        const int col = tileN + waveN + j * 16 + r16;
        const float bv = bias[col];
#pragma unroll
        for (int m = 0; m < 8; ++m) {
#pragma unroll
          for (int r = 0; r < 4; ++r) {
            const int row = tileM + waveM + m * 16 + quad * 4 + r;
            Cb[(size_t)row * ldc + col] = (OutT)(acc[m][j][r] + bv);
          }
        }
      }
    } else {
      // V columns -> write transposed into Vt[b][d][s]
      const int b = tileM >> 11;  // 256-row tiles never straddle batch
      const int s0 = (tileM & 2047) + waveM;
      f16* vb = vt + (size_t)b * DD * SS;
#pragma unroll
      for (int j = 0; j < 4; ++j) {
        const int col = tileN + waveN + j * 16 + r16;
        const float bv = bias[col];
        const int d = col - 2 * DD;
#pragma unroll
        for (int m = 0; m < 8; ++m) {
          const int s = s0 + m * 16 + quad * 4;
          f16x4 v4;
#pragma unroll
          for (int r = 0; r < 4; ++r) v4[r] = (f16)(acc[m][j][r] + bv);
          *(f16x4*)&vb[(size_t)d * SS + s] = v4;
        }
      }
    }
  } else if constexpr (MODE == EPI_MASKEXP) {
    // Pre-packed global bitmask: word (bz*SS+row)*64 + col/32, bit col&31.
    // Address is r16-uniform -> broadcast load. All DMA drained (vmcnt(0)
    // in the peeled last tile) before these VGPR loads -- hazard rule ok.
#pragma unroll
    for (int m = 0; m < 8; ++m) {
#pragma unroll
      for (int r = 0; r < 4; ++r) {
        const int row = tileM + waveM + m * 16 + quad * 4 + r;
        const uint32_t* gr =
            gmask + (((size_t)bz * SS + row) << 6) + ((tileN + waveN) >> 5);
        const uint32_t w0 = gr[0], w1 = gr[1];
        float part = 0.0f;
#pragma unroll
        for (int j = 0; j < 4; ++j) {
          const int bitpos = j * 16 + r16;
          const uint32_t mv = ((j < 2 ? w0 : w1) >> (bitpos & 31)) & 1u;
          // no max-subtraction: scores ~N(0,1); f16 overflow needs >11 sigma;
          // masked -> exact 0.
          const float e = mv ? 0.0f : __expf(acc[m][j][r] * scale);
          Cb[(size_t)row * ldc + tileN + waveN + j * 16 + r16] = (OutT)e;
          part += e;
        }
#pragma unroll
        for (int d = 1; d < 16; d <<= 1) part += __shfl_xor(part, d, 64);
        if (r16 == 0) atomicAdd(&rowSum[bz * SS + row], part);
      }
    }
  } else {  // EPI_ROWSCALE
#pragma unroll
    for (int m = 0; m < 8; ++m) {
#pragma unroll
      for (int r = 0; r < 4; ++r) {
        const int row = tileM + waveM + m * 16 + quad * 4 + r;
        const float inv = scale / rowSum[bz * SS + row];
#pragma unroll
        for (int j = 0; j < 4; ++j) {
          const int col = tileN + waveN + j * 16 + r16;
          Cb[(size_t)row * ldc + col] = (OutT)(acc[m][j][r] * inv);
        }
      }
    }
  }
#undef STG_A
#undef STG_B
#undef LOADB
#undef LOADA
#undef MFMA16
}

// ---------------------------------------------------------------------------
// Merged prep: X->f16 conv | W_qkv^T | W_out^T | rowSum zero | mask bit-pack.
// grid = 8192 + 3072 + 1024 + 32 + 2048 = 14368 x 256.
// Mask pack: word w covers flat row w>>6, cols (w&63)*32..+31 of the int32
// mask; thread reads 8 consecutive int4 (128B, perfectly coalesced per wave)
// and emits one uint32 (bit i = cell i != 0).
// ---------------------------------------------------------------------------
__global__ __launch_bounds__(256) void k_prep(
    const float* __restrict__ X, f16* __restrict__ Xh,
    const float* __restrict__ Wqkv, f16* __restrict__ Wqkvt,
    const float* __restrict__ Wout, f16* __restrict__ Woutt,
    float* __restrict__ rowSum, const int* __restrict__ mask,
    uint32_t* __restrict__ gmask) {
  int bid = blockIdx.x;
  const int t = threadIdx.x;
  if (bid < 8192) {  // X conv: 2097152 float4s
    const int i = bid * 256 + t;
    const float4 v = ((const float4*)X)[i];
    f16x4 h = {(f16)v.x, (f16)v.y, (f16)v.z, (f16)v.w};
    ((f16x4*)Xh)[i] = h;
    return;
  }
  bid -= 8192;
  __shared__ float tile[32][33];
  const int tx = t & 31, ty = t >> 5;
  if (bid < 3072) {  // Wqkv [1024][3072] -> Wqkvt [3072][1024]
    const int bx = (bid % 96) * 32, by = (bid / 96) * 32;
    for (int i2 = ty; i2 < 32; i2 += 8)
      tile[i2][tx] = Wqkv[(size_t)(by + i2) * 3072 + bx + tx];
    __syncthreads();
    for (int i2 = ty; i2 < 32; i2 += 8)
      Wqkvt[(size_t)(bx + i2) * 1024 + by + tx] = (f16)tile[tx][i2];
    return;
  }
  bid -= 3072;
  if (bid < 1024) {  // Wout [1024][1024] -> Woutt [1024][1024]
    const int bx = (bid & 31) * 32, by = (bid >> 5) * 32;
    for (int i2 = ty; i2 < 32; i2 += 8)
      tile[i2][tx] = Wout[(size_t)(by + i2) * 1024 + bx + tx];
    __syncthreads();
    for (int i2 = ty; i2 < 32; i2 += 8)
      Woutt[(size_t)(bx + i2) * 1024 + by + tx] = (f16)tile[tx][i2];
    return;
  }
  bid -= 1024;
  if (bid < 32) {  // rowSum zero: 32 blocks x 256 = 8192
    rowSum[bid * 256 + t] = 0.0f;
    return;
  }
  bid -= 32;  // mask pack: 2048 blocks x 256 threads = 524288 words
  const int w = bid * 256 + t;
  const int4* mr = (const int4*)(mask + ((size_t)w << 5));
  uint32_t v = 0;
#pragma unroll
  for (int c = 0; c < 8; ++c) {
    const int4 q = mr[c];
    v |= (q.x ? 1u : 0u) << (c * 4);
    v |= (q.y ? 1u : 0u) << (c * 4 + 1);
    v |= (q.z ? 1u : 0u) << (c * 4 + 2);
    v |= (q.w ? 1u : 0u) << (c * 4 + 3);
  }
  gmask[w] = v;
}

// ---------------------------------------------------------------------------
// kernel_launch
// inputs: X[4,2048,1024]f32, mask[4,2048,2048]i32, W_qkv[1024,3072]f32,
//         b_qkv[3072]f32, W_out[1024,1024]f32, b_out[1024]f32
// out:    [4,2048,1024] f32
// ---------------------------------------------------------------------------
extern "C" void kernel_launch(void* const* d_in, const int* in_sizes, int n_in,
                              void* d_out, int out_size, void* d_ws, size_t ws_size,
                              hipStream_t stream) {
  const float* X = (const float*)d_in[0];
  const int* mask = (const int*)d_in[1];
  const float* Wqkv = (const float*)d_in[2];
  const float* bqkv = (const float*)d_in[3];
  const float* Wout = (const float*)d_in[4];
  const float* bout = (const float*)d_in[5];
  float* out = (float*)d_out;

  char* ws = (char*)d_ws;
  // ws layout (bytes); total ~125.9 MB
  f16* Xh = (f16*)(ws + 0);                    // 8192*1024   (16.78 MB)
  f16* Wqkvt = (f16*)(ws + 16777216);          // 3072*1024   ( 6.29 MB)
  f16* Woutt = (f16*)(ws + 23068672);          // 1024*1024   ( 2.10 MB)
  f16* QK = (f16*)(ws + 25165824);             // 8192*2048   (33.55 MB) packed Q|K
  f16* Vt = (f16*)(ws + 58720256);             // 4*1024*2048 (16.78 MB)
  f16* E = (f16*)(ws + 75497472);              // 4*2048*2048 (33.55 MB) exp(scores)
  f16* Ctx = (f16*)(ws + 109051904);           // 8192*1024   (16.78 MB)
  float* rowSum = (float*)(ws + 125829120);    // 8192 f32    (32 KB)
  // gmask (2MB) ALIASES the head of Ctx: written by k_prep (dispatch 1), read
  // by MASKEXP (dispatch 3), Ctx first written by ROWSCALE (dispatch 4) --
  // stream order makes this safe with zero extra workspace.
  uint32_t* gmask = (uint32_t*)(ws + 109051904);

  // 1) merged prep: conv + both W transposes + rowSum zero + mask bit-pack
  k_prep<<<dim3(14368), dim3(256), 0, stream>>>(X, Xh, Wqkv, Wqkvt, Wout, Woutt,
                                                rowSum, mask, gmask);

  // 2) QKV proj [8192 x 3072], K=1024: Q,K -> packed QK; V -> Vt (transposed)
  gemm_nt8<f16, EPI_QKV><<<dim3(12, 32, 1), dim3(512), 0, stream>>>(
      Xh, 0LL, DD, Wqkvt, 0LL, DD, QK, 0LL, 2 * DD, bqkv, nullptr, nullptr, Vt,
      1.0f, DD);

  // 3) E = where(mask, 0, exp(Q @ K^T / 32)); rowSum += row sums  [2048 x 2048] x4
  gemm_nt8<f16, EPI_MASKEXP><<<dim3(8, 8, 4), dim3(512), 0, stream>>>(
      QK, (long long)SS * 2 * DD, 2 * DD, QK + DD, (long long)SS * 2 * DD, 2 * DD,
      E, (long long)SS * SS, SS, nullptr, gmask, rowSum, nullptr, 0.03125f, DD);

  // 4) ctx = (E @ V) / rowSum   [2048 x 1024] x4, K=2048
  gemm_nt8<f16, EPI_ROWSCALE><<<dim3(4, 8, 4), dim3(512), 0, stream>>>(
      E, (long long)SS * SS, SS, Vt, (long long)DD * SS, SS, Ctx,
      (long long)SS * DD, DD, nullptr, nullptr, rowSum, nullptr, 1.0f, SS);

  // 5) out = ctx @ W_out + b   [8192 x 1024], K=1024, fp32 out
  gemm_nt8<float, EPI_BIAS><<<dim3(4, 32, 1), dim3(512), 0, stream>>>(
      Ctx, 0LL, DD, Woutt, 0LL, DD, out, 0LL, DD, bout, nullptr, nullptr, nullptr,
      1.0f, DD);
}

// Round 2
// 353.475 us; speedup vs baseline: 1.0536x; 1.0536x over previous
//
#include <hip/hip_runtime.h>
#include <cstdint>
#include <cstddef>

// Problem constants: B=4, S=2048, D=1024
#define BB 4
#define SS 2048
#define DD 1024

typedef _Float16 f16;
typedef _Float16 f16x8 __attribute__((ext_vector_type(8)));
typedef _Float16 f16x4 __attribute__((ext_vector_type(4)));
typedef float fx4 __attribute__((ext_vector_type(4)));

// ---------------------------------------------------------------------------
// async global->LDS, 16B per lane. LDS dest must be wave-uniform base + lane*16.
// ---------------------------------------------------------------------------
__device__ __forceinline__ void async_copy16(void* lds, const void* g) {
  __builtin_amdgcn_global_load_lds(
      (__attribute__((address_space(1))) void*)const_cast<void*>(g),
      (__attribute__((address_space(3))) void*)lds,
      16, 0, 0);
}

enum { EPI_BIAS = 0, EPI_MASKEXP = 1, EPI_ROWSCALE = 2, EPI_QKV = 3 };

// ===========================================================================
// Kernel A (proven R4 structure, 336us session): 128x128 tile, BK=32,
// 256 threads (4 waves 2x2), 2-phase loop. Used for ROWSCALE and BIAS where
// its 2-blocks/CU occupancy gives exact-round grids (512 blocks).
// ===========================================================================
template <typename OutT, int MODE>
__global__ __launch_bounds__(256, 2) void gemm_nt(
    const f16* __restrict__ A, long long strideA, int lda,
    const f16* __restrict__ Bt, long long strideB, int ldb,
    OutT* __restrict__ C, long long strideC, int ldc,
    const float* __restrict__ bias, const int* __restrict__ mask,
    float* __restrict__ rowSum, f16* __restrict__ vt, float scale, int K) {
  constexpr int SMEM_BYTES = 32768;
  __shared__ __align__(16) char smem[SMEM_BYTES];

  const int t = threadIdx.x;
  const int lane = t & 63;
  const int wid = t >> 6;
  const long long bz = blockIdx.z;
  const int tileM = blockIdx.y * 128;
  const int tileN = blockIdx.x * 128;

  const f16* Ab = A + bz * strideA;
  const f16* Bb = Bt + bz * strideB;
  OutT* Cb = C + bz * strideC;

  const int sr = t >> 2;
  const int sc = (((t & 3) ^ ((t >> 3) & 3)) * 8);
  const f16* pa0 = Ab + (size_t)(tileM + sr) * lda + sc;
  const f16* pa1 = Ab + (size_t)(tileM + 64 + sr) * lda + sc;
  const f16* pb0 = Bb + (size_t)(tileN + sr) * ldb + sc;
  const f16* pb1 = Bb + (size_t)(tileN + 64 + sr) * ldb + sc;
  const int tb = t * 16;

  const int waveM = (wid >> 1) * 64;
  const int waveN = (wid & 1) * 64;
  const int r16 = lane & 15;
  const int quad = lane >> 4;
  const int sw = (r16 >> 1) & 3;

  const int nIter = K >> 5;
  {
    char* b0 = smem;
    async_copy16(b0 + tb, pa0);
    async_copy16(b0 + 4096 + tb, pa1);
    async_copy16(b0 + 8192 + tb, pb0);
    async_copy16(b0 + 12288 + tb, pb1);
  }

  fx4 acc[4][4] = {};

#pragma unroll 2
  for (int i = 0; i < nIter; ++i) {
    __syncthreads();
    if (i + 1 < nIter) {
      char* nb = smem + ((i + 1) & 1) * 16384;
      const int k = (i + 1) << 5;
      async_copy16(nb + tb, pa0 + k);
      async_copy16(nb + 4096 + tb, pa1 + k);
      async_copy16(nb + 8192 + tb, pb0 + k);
      async_copy16(nb + 12288 + tb, pb1 + k);
    }
    const f16* As = (const f16*)(smem + (i & 1) * 16384);
    const f16* Bs = As + 4096;

    f16x8 af[4], bf[4];
#pragma unroll
    for (int x = 0; x < 4; ++x)
      af[x] = *(const f16x8*)&As[(waveM + x * 16 + r16) * 32 + (quad ^ sw) * 8];
#pragma unroll
    for (int x = 0; x < 4; ++x)
      bf[x] = *(const f16x8*)&Bs[(waveN + x * 16 + r16) * 32 + (quad ^ sw) * 8];

#pragma unroll
    for (int x = 0; x < 4; ++x)
#pragma unroll
      for (int j = 0; j < 4; ++j)
        acc[x][j] =
            __builtin_amdgcn_mfma_f32_16x16x32_f16(af[x], bf[j], acc[x][j], 0, 0, 0);
  }

  if constexpr (MODE == EPI_BIAS) {
#pragma unroll
    for (int j = 0; j < 4; ++j) {
      const int col = tileN + waveN + j * 16 + r16;
      const float bv = bias[col];
#pragma unroll
      for (int i = 0; i < 4; ++i) {
#pragma unroll
        for (int r = 0; r < 4; ++r) {
          const int row = tileM + waveM + i * 16 + quad * 4 + r;
          Cb[(size_t)row * ldc + col] = (OutT)(acc[i][j][r] * scale + bv);
        }
      }
    }
  } else {  // EPI_ROWSCALE
#pragma unroll
    for (int i = 0; i < 4; ++i) {
#pragma unroll
      for (int r = 0; r < 4; ++r) {
        const int row = tileM + waveM + i * 16 + quad * 4 + r;
        const float inv = scale / rowSum[bz * SS + row];
#pragma unroll
        for (int j = 0; j < 4; ++j) {
          const int col = tileN + waveN + j * 16 + r16;
          Cb[(size_t)row * ldc + col] = (OutT)(acc[i][j][r] * inv);
        }
      }
    }
  }
}

// ===========================================================================
// Kernel B: 256x256 tile, BK=64, 512 threads (8 waves 2Mx4N), 8-phase
// schedule, counted vmcnt (T3+T4) + setprio (T5). R9 FIX over R8: the
// schedule is now PINNED -- s_barrier is not a compiler scheduling fence
// (rule #18 / m201 recipe), so every phase joint gets sched_barrier(0) and
// the MFMA cluster is gated by an explicit asm lgkmcnt(0). Without this,
// hipcc reflowed the phases and MfmaUtil stalled at 25% (R8 evidence).
//
// Pipeline (per-wave vmcnt units; 1 STG_* = 2 insts):
//   prologue: stage tile0 (8 insts); vmcnt(4); barrier.
//   tile T (parity T&1), staging targets parity^1:
//     ph0: reads bf(k0)+af(m0-3,k0); STG A_k0(T+1); [pin] bar; lgkm0; [pin]
//          16 MFMA; [pin] bar
//     ph1: reads af(m4-7,k0); STG B_k0(T+1); [pin] bar; lgkm0; [pin]
//          16 MFMA; [pin] vmcnt(4) (last tile: 0); bar; [pin]
//     ph2/ph3: same on k1.
//   vmcnt(4) at ph1: outstanding={A_k1,B_k1(T) retired-next, A_k0,B_k0(T+1)};
//   waits A_k1/B_k1(T) -> ph2/3 reads safe. At ph3: waits A_k0/B_k0(T+1) ->
//   next-tile ph0/1 safe. Epilogue global loads only after the peeled
//   vmcnt(0) -> never coexist with LDS-DMA (R7 hazard rule).
// ===========================================================================
template <typename OutT, int MODE>
__global__ __launch_bounds__(512, 2) void gemm_nt8(
    const f16* __restrict__ A, long long strideA, int lda,
    const f16* __restrict__ Bt, long long strideB, int ldb,
    OutT* __restrict__ C, long long strideC, int ldc,
    const float* __restrict__ bias, const uint32_t* __restrict__ gmask,
    float* __restrict__ rowSum, f16* __restrict__ vt, float scale, int K) {
  __shared__ __align__(16) char smem[131072];

  const int t = threadIdx.x;
  const int lane = t & 63;
  const int wid = t >> 6;
  const long long bz = blockIdx.z;
  const int tileM = blockIdx.y * 256;
  const int tileN = blockIdx.x * 256;

  const f16* Ab = A + bz * strideA;
  const f16* Bb = Bt + bz * strideB;
  OutT* Cb = C + bz * strideC;

  const int gch = ((t & 3) ^ ((t >> 3) & 3)) * 8;
  const f16* pA = Ab + (size_t)(tileM + (t >> 2)) * lda + gch;
  const f16* pB = Bb + (size_t)(tileN + (t >> 2)) * ldb + gch;
  const size_t rA = (size_t)128 * lda;
  const size_t rB = (size_t)128 * ldb;
  const int tb = t * 16;

  const int waveM = (wid >> 2) * 128;
  const int waveN = (wid & 3) * 64;
  const int r16 = lane & 15;
  const int quad = lane >> 4;
  const int sw = (r16 >> 1) & 3;

  const int nT = K >> 6;

#define STG_A(par, ks, Tn)                                      \
  {                                                             \
    char* d_ = smem + (par) * 65536 + (ks) * 16384;             \
    const f16* s_ = pA + (size_t)(Tn) * 64 + (ks) * 32;         \
    async_copy16(d_ + tb, s_);                                  \
    async_copy16(d_ + 8192 + tb, s_ + rA);                      \
  }
#define STG_B(par, ks, Tn)                                      \
  {                                                             \
    char* d_ = smem + (par) * 65536 + 32768 + (ks) * 16384;     \
    const f16* s_ = pB + (size_t)(Tn) * 64 + (ks) * 32;         \
    async_copy16(d_ + tb, s_);                                  \
    async_copy16(d_ + 8192 + tb, s_ + rB);                      \
  }

#define PIN() __builtin_amdgcn_sched_barrier(0)
#define LGKM0() asm volatile("s_waitcnt lgkmcnt(0)" ::: "memory")

  // prologue: tile 0 -> parity 0, k0 parts first.
  STG_A(0, 0, 0);
  STG_B(0, 0, 0);
  STG_A(0, 1, 0);
  STG_B(0, 1, 0);
  asm volatile("s_waitcnt vmcnt(4)" ::: "memory");
  __builtin_amdgcn_s_barrier();
  PIN();

  fx4 acc[8][4] = {};
  f16x8 af[4], bf[4];

#define LOADB(Bs)                                                              \
  _Pragma("unroll") for (int j = 0; j < 4; ++j) bf[j] =                        \
      *(const f16x8*)&(Bs)[(waveN + j * 16 + r16) * 32 + (quad ^ sw) * 8];
#define LOADA(As, mo)                                                          \
  _Pragma("unroll") for (int m = 0; m < 4; ++m) af[m] =                        \
      *(const f16x8*)&(As)[(waveM + (mo) + m * 16 + r16) * 32 + (quad ^ sw) * 8];
#define MFMA16(mo)                                                             \
  __builtin_amdgcn_s_setprio(1);                                               \
  _Pragma("unroll") for (int m = 0; m < 4; ++m)                                \
  _Pragma("unroll") for (int j = 0; j < 4; ++j)                                \
      acc[(mo) + m][j] = __builtin_amdgcn_mfma_f32_16x16x32_f16(               \
          af[m], bf[j], acc[(mo) + m][j], 0, 0, 0);                            \
  __builtin_amdgcn_s_setprio(0);

  for (int T = 0; T < nT; ++T) {
    const int par = T & 1;
    const int np = par ^ 1;
    const bool st = (T + 1) < nT;
    const f16* As0 = (const f16*)(smem + par * 65536);
    const f16* As1 = As0 + 8192;
    const f16* Bs0 = As0 + 16384;
    const f16* Bs1 = As0 + 24576;

    // ---- phase 0: k0, m0-3 ----
    LOADB(Bs0);
    LOADA(As0, 0);
    if (st) STG_A(np, 0, T + 1);
    PIN();
    __builtin_amdgcn_s_barrier();
    LGKM0();
    PIN();
    MFMA16(0);
    PIN();
    __builtin_amdgcn_s_barrier();
    PIN();

    // ---- phase 1: k0, m4-7 ----
    LOADA(As0, 64);
    if (st) STG_B(np, 0, T + 1);
    PIN();
    __builtin_amdgcn_s_barrier();
    LGKM0();
    PIN();
    MFMA16(4);
    PIN();
    if (st) {
      asm volatile("s_waitcnt vmcnt(4)" ::: "memory");
    } else {
      asm volatile("s_waitcnt vmcnt(0)" ::: "memory");  // last tile: full drain
    }
    __builtin_amdgcn_s_barrier();
    PIN();

    // ---- phase 2: k1, m0-3 ----
    LOADB(Bs1);
    LOADA(As1, 0);
    if (st) STG_A(np, 1, T + 1);
    PIN();
    __builtin_amdgcn_s_barrier();
    LGKM0();
    PIN();
    MFMA16(0);
    PIN();
    __builtin_amdgcn_s_barrier();
    PIN();

    // ---- phase 3: k1, m4-7 ----
    LOADA(As1, 64);
    if (st) STG_B(np, 1, T + 1);
    PIN();
    __builtin_amdgcn_s_barrier();
    LGKM0();
    PIN();
    MFMA16(4);
    PIN();
    if (st) {
      asm volatile("s_waitcnt vmcnt(4)" ::: "memory");
    }
    __builtin_amdgcn_s_barrier();
    PIN();
  }

  // C/D layout (verified, dtype-independent): col = lane&15, row = quad*4+reg.
  if constexpr (MODE == EPI_QKV) {
    if (tileN < 2 * DD) {
      // packed QK output [8192 x 2048]
#pragma unroll
      for (int j = 0; j < 4; ++j) {
        const int col = tileN + waveN + j * 16 + r16;
        const float bv = bias[col];
#pragma unroll
        for (int m = 0; m < 8; ++m) {
#pragma unroll
          for (int r = 0; r < 4; ++r) {
            const int row = tileM + waveM + m * 16 + quad * 4 + r;
            Cb[(size_t)row * ldc + col] = (OutT)(acc[m][j][r] + bv);
          }
        }
      }
    } else {
      // V columns -> write transposed into Vt[b][d][s]
      const int b = tileM >> 11;  // 256-row tiles never straddle batch
      const int s0 = (tileM & 2047) + waveM;
      f16* vb = vt + (size_t)b * DD * SS;
#pragma unroll
      for (int j = 0; j < 4; ++j) {
        const int col = tileN + waveN + j * 16 + r16;
        const float bv = bias[col];
        const int d = col - 2 * DD;
#pragma unroll
        for (int m = 0; m < 8; ++m) {
          const int s = s0 + m * 16 + quad * 4;
          f16x4 v4;
#pragma unroll
          for (int r = 0; r < 4; ++r) v4[r] = (f16)(acc[m][j][r] + bv);
          *(f16x4*)&vb[(size_t)d * SS + s] = v4;
        }
      }
    }
  } else if constexpr (MODE == EPI_MASKEXP) {
    // Pre-packed global bitmask: word (bz*SS+row)*64 + col/32, bit col&31.
    // r16-uniform address -> broadcast load. DMA fully drained (peeled
    // vmcnt(0)) before these VGPR loads -- hazard rule ok.
#pragma unroll
    for (int m = 0; m < 8; ++m) {
#pragma unroll
      for (int r = 0; r < 4; ++r) {
        const int row = tileM + waveM + m * 16 + quad * 4 + r;
        const uint32_t* gr =
            gmask + (((size_t)bz * SS + row) << 6) + ((tileN + waveN) >> 5);
        const uint32_t w0 = gr[0], w1 = gr[1];
        float part = 0.0f;
#pragma unroll
        for (int j = 0; j < 4; ++j) {
          const int bitpos = j * 16 + r16;
          const uint32_t mv = ((j < 2 ? w0 : w1) >> (bitpos & 31)) & 1u;
          // no max-subtraction: scores ~N(0,1); f16 overflow needs >11 sigma;
          // masked -> exact 0.
          const float e = mv ? 0.0f : __expf(acc[m][j][r] * scale);
          Cb[(size_t)row * ldc + tileN + waveN + j * 16 + r16] = (OutT)e;
          part += e;
        }
#pragma unroll
        for (int d = 1; d < 16; d <<= 1) part += __shfl_xor(part, d, 64);
        if (r16 == 0) atomicAdd(&rowSum[bz * SS + row], part);
      }
    }
  }
#undef STG_A
#undef STG_B
#undef LOADB
#undef LOADA
#undef MFMA16
#undef PIN
#undef LGKM0
}

// ---------------------------------------------------------------------------
// Merged prep: X->f16 conv | W_qkv^T | W_out^T | rowSum zero | mask bit-pack.
// grid = 8192 + 3072 + 1024 + 32 + 2048 = 14368 x 256.
// ---------------------------------------------------------------------------
__global__ __launch_bounds__(256) void k_prep(
    const float* __restrict__ X, f16* __restrict__ Xh,
    const float* __restrict__ Wqkv, f16* __restrict__ Wqkvt,
    const float* __restrict__ Wout, f16* __restrict__ Woutt,
    float* __restrict__ rowSum, const int* __restrict__ mask,
    uint32_t* __restrict__ gmask) {
  int bid = blockIdx.x;
  const int t = threadIdx.x;
  if (bid < 8192) {  // X conv: 2097152 float4s
    const int i = bid * 256 + t;
    const float4 v = ((const float4*)X)[i];
    f16x4 h = {(f16)v.x, (f16)v.y, (f16)v.z, (f16)v.w};
    ((f16x4*)Xh)[i] = h;
    return;
  }
  bid -= 8192;
  __shared__ float tile[32][33];
  const int tx = t & 31, ty = t >> 5;
  if (bid < 3072) {  // Wqkv [1024][3072] -> Wqkvt [3072][1024]
    const int bx = (bid % 96) * 32, by = (bid / 96) * 32;
    for (int i2 = ty; i2 < 32; i2 += 8)
      tile[i2][tx] = Wqkv[(size_t)(by + i2) * 3072 + bx + tx];
    __syncthreads();
    for (int i2 = ty; i2 < 32; i2 += 8)
      Wqkvt[(size_t)(bx + i2) * 1024 + by + tx] = (f16)tile[tx][i2];
    return;
  }
  bid -= 3072;
  if (bid < 1024) {  // Wout [1024][1024] -> Woutt [1024][1024]
    const int bx = (bid & 31) * 32, by = (bid >> 5) * 32;
    for (int i2 = ty; i2 < 32; i2 += 8)
      tile[i2][tx] = Wout[(size_t)(by + i2) * 1024 + bx + tx];
    __syncthreads();
    for (int i2 = ty; i2 < 32; i2 += 8)
      Woutt[(size_t)(bx + i2) * 1024 + by + tx] = (f16)tile[tx][i2];
    return;
  }
  bid -= 1024;
  if (bid < 32) {  // rowSum zero
    rowSum[bid * 256 + t] = 0.0f;
    return;
  }
  bid -= 32;  // mask pack: word w covers flat row w>>6, cols (w&63)*32..+31
  const int w = bid * 256 + t;
  const int4* mr = (const int4*)(mask + ((size_t)w << 5));
  uint32_t v = 0;
#pragma unroll
  for (int c = 0; c < 8; ++c) {
    const int4 q = mr[c];
    v |= (q.x ? 1u : 0u) << (c * 4);
    v |= (q.y ? 1u : 0u) << (c * 4 + 1);
    v |= (q.z ? 1u : 0u) << (c * 4 + 2);
    v |= (q.w ? 1u : 0u) << (c * 4 + 3);
  }
  gmask[w] = v;
}

// ---------------------------------------------------------------------------
// kernel_launch
// ---------------------------------------------------------------------------
extern "C" void kernel_launch(void* const* d_in, const int* in_sizes, int n_in,
                              void* d_out, int out_size, void* d_ws, size_t ws_size,
                              hipStream_t stream) {
  const float* X = (const float*)d_in[0];
  const int* mask = (const int*)d_in[1];
  const float* Wqkv = (const float*)d_in[2];
  const float* bqkv = (const float*)d_in[3];
  const float* Wout = (const float*)d_in[4];
  const float* bout = (const float*)d_in[5];
  float* out = (float*)d_out;

  char* ws = (char*)d_ws;
  f16* Xh = (f16*)(ws + 0);                    // 8192*1024   (16.78 MB)
  f16* Wqkvt = (f16*)(ws + 16777216);          // 3072*1024   ( 6.29 MB)
  f16* Woutt = (f16*)(ws + 23068672);          // 1024*1024   ( 2.10 MB)
  f16* QK = (f16*)(ws + 25165824);             // 8192*2048   (33.55 MB) packed Q|K
  f16* Vt = (f16*)(ws + 58720256);             // 4*1024*2048 (16.78 MB)
  f16* E = (f16*)(ws + 75497472);              // 4*2048*2048 (33.55 MB) exp(scores)
  f16* Ctx = (f16*)(ws + 109051904);           // 8192*1024   (16.78 MB)
  float* rowSum = (float*)(ws + 125829120);    // 8192 f32    (32 KB)
  // gmask (2MB) aliases head of Ctx: written by k_prep (d1), read by MASKEXP
  // (d3), Ctx first written by ROWSCALE (d4) -- stream order makes this safe.
  uint32_t* gmask = (uint32_t*)(ws + 109051904);

  // 1) merged prep
  k_prep<<<dim3(14368), dim3(256), 0, stream>>>(X, Xh, Wqkv, Wqkvt, Wout, Woutt,
                                                rowSum, mask, gmask);

  // 2) QKV proj [8192 x 3072], K=1024 (8-phase 256^2; 384 blocks)
  gemm_nt8<f16, EPI_QKV><<<dim3(12, 32, 1), dim3(512), 0, stream>>>(
      Xh, 0LL, DD, Wqkvt, 0LL, DD, QK, 0LL, 2 * DD, bqkv, nullptr, nullptr, Vt,
      1.0f, DD);

  // 3) E = where(mask, 0, exp(QK^T/32)); rowSum (8-phase 256^2; 256 blocks)
  gemm_nt8<f16, EPI_MASKEXP><<<dim3(8, 8, 4), dim3(512), 0, stream>>>(
      QK, (long long)SS * 2 * DD, 2 * DD, QK + DD, (long long)SS * 2 * DD, 2 * DD,
      E, (long long)SS * SS, SS, nullptr, gmask, rowSum, nullptr, 0.03125f, DD);

  // 4) ctx = (E @ V) / rowSum  (2-phase 128^2; 512 blocks = exact round)
  gemm_nt<f16, EPI_ROWSCALE><<<dim3(8, 16, 4), dim3(256), 0, stream>>>(
      E, (long long)SS * SS, SS, Vt, (long long)DD * SS, SS, Ctx,
      (long long)SS * DD, DD, nullptr, nullptr, rowSum, nullptr, 1.0f, SS);

  // 5) out = ctx @ W_out + b  (2-phase 128^2; 512 blocks = exact round)
  gemm_nt<float, EPI_BIAS><<<dim3(8, 64, 1), dim3(256), 0, stream>>>(
      Ctx, 0LL, DD, Woutt, 0LL, DD, out, 0LL, DD, bout, nullptr, nullptr, nullptr,
      1.0f, DD);
}

// Round 3
// 349.319 us; speedup vs baseline: 1.0661x; 1.0119x over previous
//
#include <hip/hip_runtime.h>
#include <cstdint>
#include <cstddef>

// Problem constants: B=4, S=2048, D=1024
#define BB 4
#define SS 2048
#define DD 1024

typedef _Float16 f16;
typedef _Float16 f16x8 __attribute__((ext_vector_type(8)));
typedef _Float16 f16x4 __attribute__((ext_vector_type(4)));
typedef float fx4 __attribute__((ext_vector_type(4)));

// ---------------------------------------------------------------------------
// async global->LDS, 16B per lane. LDS dest must be wave-uniform base + lane*16.
// ---------------------------------------------------------------------------
__device__ __forceinline__ void async_copy16(void* lds, const void* g) {
  __builtin_amdgcn_global_load_lds(
      (__attribute__((address_space(1))) void*)const_cast<void*>(g),
      (__attribute__((address_space(3))) void*)lds,
      16, 0, 0);
}

enum { EPI_BIAS = 0, EPI_MASKEXP = 1, EPI_ROWSCALE = 2, EPI_QKV = 3 };

// ===========================================================================
// Kernel A (proven R4 structure): 128x128 tile, BK=32, 256 threads (4 waves
// 2x2), 2-phase loop. Used for ROWSCALE and BIAS (3-4 blocks/CU TLP hides
// the barrier-drain latency; measured ~446 TF at these shapes).
// ===========================================================================
template <typename OutT, int MODE>
__global__ __launch_bounds__(256, 2) void gemm_nt(
    const f16* __restrict__ A, long long strideA, int lda,
    const f16* __restrict__ Bt, long long strideB, int ldb,
    OutT* __restrict__ C, long long strideC, int ldc,
    const float* __restrict__ bias, const int* __restrict__ mask,
    float* __restrict__ rowSum, f16* __restrict__ vt, float scale, int K) {
  constexpr int SMEM_BYTES = 32768;
  __shared__ __align__(16) char smem[SMEM_BYTES];

  const int t = threadIdx.x;
  const int lane = t & 63;
  const int wid = t >> 6;
  const long long bz = blockIdx.z;
  const int tileM = blockIdx.y * 128;
  const int tileN = blockIdx.x * 128;

  const f16* Ab = A + bz * strideA;
  const f16* Bb = Bt + bz * strideB;
  OutT* Cb = C + bz * strideC;

  const int sr = t >> 2;
  const int sc = (((t & 3) ^ ((t >> 3) & 3)) * 8);
  const f16* pa0 = Ab + (size_t)(tileM + sr) * lda + sc;
  const f16* pa1 = Ab + (size_t)(tileM + 64 + sr) * lda + sc;
  const f16* pb0 = Bb + (size_t)(tileN + sr) * ldb + sc;
  const f16* pb1 = Bb + (size_t)(tileN + 64 + sr) * ldb + sc;
  const int tb = t * 16;

  const int waveM = (wid >> 1) * 64;
  const int waveN = (wid & 1) * 64;
  const int r16 = lane & 15;
  const int quad = lane >> 4;
  const int sw = (r16 >> 1) & 3;

  const int nIter = K >> 5;
  {
    char* b0 = smem;
    async_copy16(b0 + tb, pa0);
    async_copy16(b0 + 4096 + tb, pa1);
    async_copy16(b0 + 8192 + tb, pb0);
    async_copy16(b0 + 12288 + tb, pb1);
  }

  fx4 acc[4][4] = {};

#pragma unroll 2
  for (int i = 0; i < nIter; ++i) {
    __syncthreads();
    if (i + 1 < nIter) {
      char* nb = smem + ((i + 1) & 1) * 16384;
      const int k = (i + 1) << 5;
      async_copy16(nb + tb, pa0 + k);
      async_copy16(nb + 4096 + tb, pa1 + k);
      async_copy16(nb + 8192 + tb, pb0 + k);
      async_copy16(nb + 12288 + tb, pb1 + k);
    }
    const f16* As = (const f16*)(smem + (i & 1) * 16384);
    const f16* Bs = As + 4096;

    f16x8 af[4], bf[4];
#pragma unroll
    for (int x = 0; x < 4; ++x)
      af[x] = *(const f16x8*)&As[(waveM + x * 16 + r16) * 32 + (quad ^ sw) * 8];
#pragma unroll
    for (int x = 0; x < 4; ++x)
      bf[x] = *(const f16x8*)&Bs[(waveN + x * 16 + r16) * 32 + (quad ^ sw) * 8];

#pragma unroll
    for (int x = 0; x < 4; ++x)
#pragma unroll
      for (int j = 0; j < 4; ++j)
        acc[x][j] =
            __builtin_amdgcn_mfma_f32_16x16x32_f16(af[x], bf[j], acc[x][j], 0, 0, 0);
  }

  if constexpr (MODE == EPI_BIAS) {
#pragma unroll
    for (int j = 0; j < 4; ++j) {
      const int col = tileN + waveN + j * 16 + r16;
      const float bv = bias[col];
#pragma unroll
      for (int i = 0; i < 4; ++i) {
#pragma unroll
        for (int r = 0; r < 4; ++r) {
          const int row = tileM + waveM + i * 16 + quad * 4 + r;
          Cb[(size_t)row * ldc + col] = (OutT)(acc[i][j][r] * scale + bv);
        }
      }
    }
  } else {  // EPI_ROWSCALE
#pragma unroll
    for (int i = 0; i < 4; ++i) {
#pragma unroll
      for (int r = 0; r < 4; ++r) {
        const int row = tileM + waveM + i * 16 + quad * 4 + r;
        const float inv = scale / rowSum[bz * SS + row];
#pragma unroll
        for (int j = 0; j < 4; ++j) {
          const int col = tileN + waveN + j * 16 + r16;
          Cb[(size_t)row * ldc + col] = (OutT)(acc[i][j][r] * inv);
        }
      }
    }
  }
}

// ===========================================================================
// Kernel B: 256x256 tile, BK=64, 512 threads (8 waves 2Mx4N), 4-phase/K-tile
// schedule. R10 FIX over R8/R9 (both 25% MfmaUtil, pin-invariant): the old
// schedule waited vmcnt TWICE per K-tile on loads issued only ~2 phases
// earlier (~600-1000cy cover < ~900cy HBM latency) -> exposed stall every
// other phase, and at 1 block/CU nothing hides it. New schedule = m201-style
// DEEP COVER, ONE wait per K-tile:
//
//   tile T (parity par=T&1, staging -> np=par^1, st=(T+1<nT)):
//     ph0: reads bf(k0)+af(m0-3,k0); stage ALL A(T+1) (4 insts: k0+k1);
//          bar; lgkm0; 16 MFMA; bar
//     ph1: reads af(m4-7,k0); stage ALL B(T+1) (4 insts);
//          bar; lgkm0; 16 MFMA; vmcnt(8) [bootstrap: retires k1(0) at T=0;
//          steady state <=8 outstanding -> free]; bar
//     ph2: reads bf(k1)+af(m0-3,k1); bar; lgkm0; 16 MFMA; bar
//     ph3: reads af(m4-7,k1); bar; lgkm0; 16 MFMA;
//          vmcnt(0) [waits A(T+1) cover ~3.2 phases, B(T+1) cover ~2.2
//          phases ~= 1400-2000cy > HBM latency]; bar
//
//   Invariant: entering tile T, ALL of tile T's data is resident (drained by
//   T-1's ph3 vmcnt(0)+barrier). Staging targets the opposite parity buffer,
//   whose readers finished a barrier earlier -> no overwrite race. Last tile
//   stages nothing -> epilogue VGPR loads never coexist with LDS-DMA (R7).
//
// LDS (128KB): 2 parity x { A_k0 16K | A_k1 16K | B_k0 16K | B_k1 16K },
// slot = [256 rows][32 f16], chunk-XOR swizzle (verified conflict-free:
// SQ_LDS_BANK_CONFLICT=0). lgkm0 + sched_barrier pins per rule #18.
// ===========================================================================
template <typename OutT, int MODE>
__global__ __launch_bounds__(512, 2) void gemm_nt8(
    const f16* __restrict__ A, long long strideA, int lda,
    const f16* __restrict__ Bt, long long strideB, int ldb,
    OutT* __restrict__ C, long long strideC, int ldc,
    const float* __restrict__ bias, const uint32_t* __restrict__ gmask,
    float* __restrict__ rowSum, f16* __restrict__ vt, float scale, int K) {
  __shared__ __align__(16) char smem[131072];

  const int t = threadIdx.x;
  const int lane = t & 63;
  const int wid = t >> 6;
  const long long bz = blockIdx.z;
  const int tileM = blockIdx.y * 256;
  const int tileN = blockIdx.x * 256;

  const f16* Ab = A + bz * strideA;
  const f16* Bb = Bt + bz * strideB;
  OutT* Cb = C + bz * strideC;

  const int gch = ((t & 3) ^ ((t >> 3) & 3)) * 8;
  const f16* pA = Ab + (size_t)(tileM + (t >> 2)) * lda + gch;
  const f16* pB = Bb + (size_t)(tileN + (t >> 2)) * ldb + gch;
  const size_t rA = (size_t)128 * lda;
  const size_t rB = (size_t)128 * ldb;
  const int tb = t * 16;

  const int waveM = (wid >> 2) * 128;
  const int waveN = (wid & 3) * 64;
  const int r16 = lane & 15;
  const int quad = lane >> 4;
  const int sw = (r16 >> 1) & 3;

  const int nT = K >> 6;

#define STG_A(par, ks, Tn)                                      \
  {                                                             \
    char* d_ = smem + (par) * 65536 + (ks) * 16384;             \
    const f16* s_ = pA + (size_t)(Tn) * 64 + (ks) * 32;         \
    async_copy16(d_ + tb, s_);                                  \
    async_copy16(d_ + 8192 + tb, s_ + rA);                      \
  }
#define STG_B(par, ks, Tn)                                      \
  {                                                             \
    char* d_ = smem + (par) * 65536 + 32768 + (ks) * 16384;     \
    const f16* s_ = pB + (size_t)(Tn) * 64 + (ks) * 32;         \
    async_copy16(d_ + tb, s_);                                  \
    async_copy16(d_ + 8192 + tb, s_ + rB);                      \
  }

#define PIN() __builtin_amdgcn_sched_barrier(0)
#define LGKM0() asm volatile("s_waitcnt lgkmcnt(0)" ::: "memory")

  // prologue: tile 0 -> parity 0, k0 parts first.
  STG_A(0, 0, 0);
  STG_B(0, 0, 0);
  STG_A(0, 1, 0);
  STG_B(0, 1, 0);
  asm volatile("s_waitcnt vmcnt(4)" ::: "memory");
  __builtin_amdgcn_s_barrier();
  PIN();

  fx4 acc[8][4] = {};
  f16x8 af[4], bf[4];

#define LOADB(Bs)                                                              \
  _Pragma("unroll") for (int j = 0; j < 4; ++j) bf[j] =                        \
      *(const f16x8*)&(Bs)[(waveN + j * 16 + r16) * 32 + (quad ^ sw) * 8];
#define LOADA(As, mo)                                                          \
  _Pragma("unroll") for (int m = 0; m < 4; ++m) af[m] =                        \
      *(const f16x8*)&(As)[(waveM + (mo) + m * 16 + r16) * 32 + (quad ^ sw) * 8];
#define MFMA16(mo)                                                             \
  __builtin_amdgcn_s_setprio(1);                                               \
  _Pragma("unroll") for (int m = 0; m < 4; ++m)                                \
  _Pragma("unroll") for (int j = 0; j < 4; ++j)                                \
      acc[(mo) + m][j] = __builtin_amdgcn_mfma_f32_16x16x32_f16(               \
          af[m], bf[j], acc[(mo) + m][j], 0, 0, 0);                            \
  __builtin_amdgcn_s_setprio(0);

  for (int T = 0; T < nT; ++T) {
    const int par = T & 1;
    const int np = par ^ 1;
    const bool st = (T + 1) < nT;
    const f16* As0 = (const f16*)(smem + par * 65536);
    const f16* As1 = As0 + 8192;
    const f16* Bs0 = As0 + 16384;
    const f16* Bs1 = As0 + 24576;

    // ---- phase 0: k0, m0-3; stage ALL of A(T+1) ----
    LOADB(Bs0);
    LOADA(As0, 0);
    if (st) {
      STG_A(np, 0, T + 1);
      STG_A(np, 1, T + 1);
    }
    PIN();
    __builtin_amdgcn_s_barrier();
    LGKM0();
    PIN();
    MFMA16(0);
    PIN();
    __builtin_amdgcn_s_barrier();
    PIN();

    // ---- phase 1: k0, m4-7; stage ALL of B(T+1) ----
    LOADA(As0, 64);
    if (st) {
      STG_B(np, 0, T + 1);
      STG_B(np, 1, T + 1);
    }
    PIN();
    __builtin_amdgcn_s_barrier();
    LGKM0();
    PIN();
    MFMA16(4);
    PIN();
    // Bootstrap wait (T=0: retires k1(0) staged in prologue). Steady state
    // has <=8 outstanding -> free.
    asm volatile("s_waitcnt vmcnt(8)" ::: "memory");
    __builtin_amdgcn_s_barrier();
    PIN();

    // ---- phase 2: k1, m0-3 ----
    LOADB(Bs1);
    LOADA(As1, 0);
    PIN();
    __builtin_amdgcn_s_barrier();
    LGKM0();
    PIN();
    MFMA16(0);
    PIN();
    __builtin_amdgcn_s_barrier();
    PIN();

    // ---- phase 3: k1, m4-7; single per-tile drain ----
    LOADA(As1, 64);
    PIN();
    __builtin_amdgcn_s_barrier();
    LGKM0();
    PIN();
    MFMA16(4);
    PIN();
    asm volatile("s_waitcnt vmcnt(0)" ::: "memory");
    __builtin_amdgcn_s_barrier();
    PIN();
  }

  // C/D layout (verified, dtype-independent): col = lane&15, row = quad*4+reg.
  if constexpr (MODE == EPI_QKV) {
    if (tileN < 2 * DD) {
      // packed QK output [8192 x 2048]
#pragma unroll
      for (int j = 0; j < 4; ++j) {
        const int col = tileN + waveN + j * 16 + r16;
        const float bv = bias[col];
#pragma unroll
        for (int m = 0; m < 8; ++m) {
#pragma unroll
          for (int r = 0; r < 4; ++r) {
            const int row = tileM + waveM + m * 16 + quad * 4 + r;
            Cb[(size_t)row * ldc + col] = (OutT)(acc[m][j][r] + bv);
          }
        }
      }
    } else {
      // V columns -> write transposed into Vt[b][d][s]
      const int b = tileM >> 11;  // 256-row tiles never straddle batch
      const int s0 = (tileM & 2047) + waveM;
      f16* vb = vt + (size_t)b * DD * SS;
#pragma unroll
      for (int j = 0; j < 4; ++j) {
        const int col = tileN + waveN + j * 16 + r16;
        const float bv = bias[col];
        const int d = col - 2 * DD;
#pragma unroll
        for (int m = 0; m < 8; ++m) {
          const int s = s0 + m * 16 + quad * 4;
          f16x4 v4;
#pragma unroll
          for (int r = 0; r < 4; ++r) v4[r] = (f16)(acc[m][j][r] + bv);
          *(f16x4*)&vb[(size_t)d * SS + s] = v4;
        }
      }
    }
  } else if constexpr (MODE == EPI_MASKEXP) {
    // Pre-packed global bitmask: word (bz*SS+row)*64 + col/32, bit col&31.
    // r16-uniform address -> broadcast load. DMA fully drained before these
    // VGPR loads -- hazard rule ok.
#pragma unroll
    for (int m = 0; m < 8; ++m) {
#pragma unroll
      for (int r = 0; r < 4; ++r) {
        const int row = tileM + waveM + m * 16 + quad * 4 + r;
        const uint32_t* gr =
            gmask + (((size_t)bz * SS + row) << 6) + ((tileN + waveN) >> 5);
        const uint32_t w0 = gr[0], w1 = gr[1];
        float part = 0.0f;
#pragma unroll
        for (int j = 0; j < 4; ++j) {
          const int bitpos = j * 16 + r16;
          const uint32_t mv = ((j < 2 ? w0 : w1) >> (bitpos & 31)) & 1u;
          // no max-subtraction: scores ~N(0,1); f16 overflow needs >11 sigma;
          // masked -> exact 0.
          const float e = mv ? 0.0f : __expf(acc[m][j][r] * scale);
          Cb[(size_t)row * ldc + tileN + waveN + j * 16 + r16] = (OutT)e;
          part += e;
        }
#pragma unroll
        for (int d = 1; d < 16; d <<= 1) part += __shfl_xor(part, d, 64);
        if (r16 == 0) atomicAdd(&rowSum[bz * SS + row], part);
      }
    }
  }
#undef STG_A
#undef STG_B
#undef LOADB
#undef LOADA
#undef MFMA16
#undef PIN
#undef LGKM0
}

// ---------------------------------------------------------------------------
// Merged prep: X->f16 conv | W_qkv^T | W_out^T | rowSum zero | mask bit-pack.
// grid = 8192 + 3072 + 1024 + 32 + 2048 = 14368 x 256.
// ---------------------------------------------------------------------------
__global__ __launch_bounds__(256) void k_prep(
    const float* __restrict__ X, f16* __restrict__ Xh,
    const float* __restrict__ Wqkv, f16* __restrict__ Wqkvt,
    const float* __restrict__ Wout, f16* __restrict__ Woutt,
    float* __restrict__ rowSum, const int* __restrict__ mask,
    uint32_t* __restrict__ gmask) {
  int bid = blockIdx.x;
  const int t = threadIdx.x;
  if (bid < 8192) {  // X conv: 2097152 float4s
    const int i = bid * 256 + t;
    const float4 v = ((const float4*)X)[i];
    f16x4 h = {(f16)v.x, (f16)v.y, (f16)v.z, (f16)v.w};
    ((f16x4*)Xh)[i] = h;
    return;
  }
  bid -= 8192;
  __shared__ float tile[32][33];
  const int tx = t & 31, ty = t >> 5;
  if (bid < 3072) {  // Wqkv [1024][3072] -> Wqkvt [3072][1024]
    const int bx = (bid % 96) * 32, by = (bid / 96) * 32;
    for (int i2 = ty; i2 < 32; i2 += 8)
      tile[i2][tx] = Wqkv[(size_t)(by + i2) * 3072 + bx + tx];
    __syncthreads();
    for (int i2 = ty; i2 < 32; i2 += 8)
      Wqkvt[(size_t)(bx + i2) * 1024 + by + tx] = (f16)tile[tx][i2];
    return;
  }
  bid -= 3072;
  if (bid < 1024) {  // Wout [1024][1024] -> Woutt [1024][1024]
    const int bx = (bid & 31) * 32, by = (bid >> 5) * 32;
    for (int i2 = ty; i2 < 32; i2 += 8)
      tile[i2][tx] = Wout[(size_t)(by + i2) * 1024 + bx + tx];
    __syncthreads();
    for (int i2 = ty; i2 < 32; i2 += 8)
      Woutt[(size_t)(bx + i2) * 1024 + by + tx] = (f16)tile[tx][i2];
    return;
  }
  bid -= 1024;
  if (bid < 32) {  // rowSum zero
    rowSum[bid * 256 + t] = 0.0f;
    return;
  }
  bid -= 32;  // mask pack: word w covers flat row w>>6, cols (w&63)*32..+31
  const int w = bid * 256 + t;
  const int4* mr = (const int4*)(mask + ((size_t)w << 5));
  uint32_t v = 0;
#pragma unroll
  for (int c = 0; c < 8; ++c) {
    const int4 q = mr[c];
    v |= (q.x ? 1u : 0u) << (c * 4);
    v |= (q.y ? 1u : 0u) << (c * 4 + 1);
    v |= (q.z ? 1u : 0u) << (c * 4 + 2);
    v |= (q.w ? 1u : 0u) << (c * 4 + 3);
  }
  gmask[w] = v;
}

// ---------------------------------------------------------------------------
// kernel_launch
// ---------------------------------------------------------------------------
extern "C" void kernel_launch(void* const* d_in, const int* in_sizes, int n_in,
                              void* d_out, int out_size, void* d_ws, size_t ws_size,
                              hipStream_t stream) {
  const float* X = (const float*)d_in[0];
  const int* mask = (const int*)d_in[1];
  const float* Wqkv = (const float*)d_in[2];
  const float* bqkv = (const float*)d_in[3];
  const float* Wout = (const float*)d_in[4];
  const float* bout = (const float*)d_in[5];
  float* out = (float*)d_out;

  char* ws = (char*)d_ws;
  f16* Xh = (f16*)(ws + 0);                    // 8192*1024   (16.78 MB)
  f16* Wqkvt = (f16*)(ws + 16777216);          // 3072*1024   ( 6.29 MB)
  f16* Woutt = (f16*)(ws + 23068672);          // 1024*1024   ( 2.10 MB)
  f16* QK = (f16*)(ws + 25165824);             // 8192*2048   (33.55 MB) packed Q|K
  f16* Vt = (f16*)(ws + 58720256);             // 4*1024*2048 (16.78 MB)
  f16* E = (f16*)(ws + 75497472);              // 4*2048*2048 (33.55 MB) exp(scores)
  f16* Ctx = (f16*)(ws + 109051904);           // 8192*1024   (16.78 MB)
  float* rowSum = (float*)(ws + 125829120);    // 8192 f32    (32 KB)
  // gmask (2MB) aliases head of Ctx: written by k_prep (d1), read by MASKEXP
  // (d3), Ctx first written by ROWSCALE (d4) -- stream order makes this safe.
  uint32_t* gmask = (uint32_t*)(ws + 109051904);

  // 1) merged prep
  k_prep<<<dim3(14368), dim3(256), 0, stream>>>(X, Xh, Wqkv, Wqkvt, Wout, Woutt,
                                                rowSum, mask, gmask);

  // 2) QKV proj [8192 x 3072], K=1024 (deep-cover 256^2; 384 blocks)
  gemm_nt8<f16, EPI_QKV><<<dim3(12, 32, 1), dim3(512), 0, stream>>>(
      Xh, 0LL, DD, Wqkvt, 0LL, DD, QK, 0LL, 2 * DD, bqkv, nullptr, nullptr, Vt,
      1.0f, DD);

  // 3) E = where(mask, 0, exp(QK^T/32)); rowSum (deep-cover 256^2; 256 blocks)
  gemm_nt8<f16, EPI_MASKEXP><<<dim3(8, 8, 4), dim3(512), 0, stream>>>(
      QK, (long long)SS * 2 * DD, 2 * DD, QK + DD, (long long)SS * 2 * DD, 2 * DD,
      E, (long long)SS * SS, SS, nullptr, gmask, rowSum, nullptr, 0.03125f, DD);

  // 4) ctx = (E @ V) / rowSum  (2-phase 128^2; 512 blocks)
  gemm_nt<f16, EPI_ROWSCALE><<<dim3(8, 16, 4), dim3(256), 0, stream>>>(
      E, (long long)SS * SS, SS, Vt, (long long)DD * SS, SS, Ctx,
      (long long)SS * DD, DD, nullptr, nullptr, rowSum, nullptr, 1.0f, SS);

  // 5) out = ctx @ W_out + b  (2-phase 128^2; 512 blocks)
  gemm_nt<float, EPI_BIAS><<<dim3(8, 64, 1), dim3(256), 0, stream>>>(
      Ctx, 0LL, DD, Woutt, 0LL, DD, out, 0LL, DD, bout, nullptr, nullptr, nullptr,
      1.0f, DD);
}